// Round 3
// baseline (531.291 us; speedup 1.0000x reference)
//
#include <hip/hip_runtime.h>
#include <hip/hip_fp16.h>

#define N_NODES 100000
#define N_EDGES 1600000
#define NBUCKET 196          // ceil(100000 / 512)
#define CAP     8960         // per-bucket capacity: mean 8163, sigma 90 -> +8.8 sigma
#define EPB     6250         // edges per block in partition (256 blocks)

typedef _Float16 half8 __attribute__((ext_vector_type(8)));
typedef float float4v __attribute__((ext_vector_type(4)));

// acc += (float)lo_half(w)  /  acc += (float)hi_half(w)  in ONE VALU op each.
__device__ __forceinline__ void fmix_lo(float& a, unsigned int w, float one) {
    asm("v_fma_mix_f32 %0, %1, %2, %0 op_sel:[0,0,0] op_sel_hi:[1,0,0]"
        : "+v"(a) : "v"(w), "v"(one));
}
__device__ __forceinline__ void fmix_hi(float& a, unsigned int w, float one) {
    asm("v_fma_mix_f32 %0, %1, %2, %0 op_sel:[1,0,0] op_sel_hi:[1,0,0]"
        : "+v"(a) : "v"(w), "v"(one));
}

// ---------------- partition edges into fixed-capacity bucket segments
__launch_bounds__(256)
__global__ void k_part_wswz(const int* __restrict__ src, const int* __restrict__ dst,
                            int* __restrict__ bcur, int* __restrict__ ebuf, int E,
                            const float* __restrict__ W1, const float* __restrict__ W2,
                            const float* __restrict__ W3, _Float16* __restrict__ wz1,
                            _Float16* __restrict__ wz2, _Float16* __restrict__ wz3) {
    if (blockIdx.x >= 256) {
        int t = (blockIdx.x - 256) * 256 + threadIdx.x;
        const float* W; _Float16* wsz; int BN;
        if (t < 2048)      { W = W1; wsz = wz1; BN = 128; }
        else if (t < 4096) { W = W2; wsz = wz2; BN = 128; t -= 2048; }
        else if (t < 5120) { W = W3; wsz = wz3; BN = 64;  t -= 4096; }
        else return;
        const int l = t & 63;
        const int kblk = (t >> 6) & 3;
        const int nt = t >> 8;
        const int krow = kblk * 32 + ((l >> 4) << 3);
        const int col = nt * 16 + (l & 15);
        _Float16 v[8];
#pragma unroll
        for (int j = 0; j < 8; ++j) v[j] = (_Float16)W[(krow + j) * BN + col];
        *(uint4*)&wsz[t << 3] = *(uint4*)v;
        return;
    }
    __shared__ int hist[200];
    __shared__ int basebkt[200];
    const int tid = threadIdx.x;
    if (tid < 200) hist[tid] = 0;
    __syncthreads();
    const int e0 = blockIdx.x * EPB, e1 = min(e0 + EPB, E);
    for (int e = e0 + tid; e < e1; e += 256) atomicAdd(&hist[dst[e] >> 9], 1);
    __syncthreads();
    if (tid < NBUCKET) {
        int h = hist[tid];
        basebkt[tid] = tid * CAP + (h ? atomicAdd(&bcur[tid], h) : 0);
    }
    __syncthreads();
    if (tid < 200) hist[tid] = 0;
    __syncthreads();
    for (int e = e0 + tid; e < e1; e += 256) {
        int d = dst[e];
        int bk = d >> 9;
        int o = atomicAdd(&hist[bk], 1);
        ebuf[basebkt[bk] + o] = (src[e] << 9) | (d & 511);
    }
}

// ---------------- per-bucket counting sort -> deg, stv, dinv, adj (bucketed layout)
__launch_bounds__(256)
__global__ void k_bsort(const int* __restrict__ ebuf, const int* __restrict__ bcur,
                        int* __restrict__ adj, int* __restrict__ stv,
                        int* __restrict__ deg, float* __restrict__ dinv, int N) {
    __shared__ int cnt[512];
    __shared__ int offs[512];
    const int b = blockIdx.x;
    const int tid = threadIdx.x;
    const int base = b * CAP;
    const int n_b = min(bcur[b], CAP);
    const int node0 = b << 9;
    cnt[tid] = 0; cnt[tid + 256] = 0;
    __syncthreads();
    for (int i = tid; i < n_b; i += 256)
        atomicAdd(&cnt[ebuf[base + i] & 511], 1);
    __syncthreads();
    if (tid < 64) {  // wave-0 exclusive scan of 512
        int v[8], tot = 0;
#pragma unroll
        for (int j = 0; j < 8; ++j) { int t = cnt[tid * 8 + j]; v[j] = tot; tot += t; }
        int inc = tot;
#pragma unroll
        for (int d = 1; d < 64; d <<= 1) {
            int u = __shfl_up(inc, d, 64);
            if (tid >= d) inc += u;
        }
        const int excl = inc - tot;
#pragma unroll
        for (int j = 0; j < 8; ++j) offs[tid * 8 + j] = excl + v[j];
    }
    __syncthreads();
#pragma unroll
    for (int h = 0; h < 2; ++h) {
        int local = tid + h * 256;
        int node = node0 + local;
        if (node < N) {
            stv[node] = base + offs[local];
            deg[node] = cnt[local];
            dinv[node] = rsqrtf((float)(cnt[local] + 1));
        }
    }
    __syncthreads();
    for (int i = tid; i < n_b; i += 256) {  // offs doubles as cursor
        int pk = ebuf[base + i];
        int pos = atomicAdd(&offs[pk & 511], 1);
        adj[base + pos] = pk >> 9;
    }
}

// ---------------- MFMA GEMM: tp[i][:] = fp16( dinv[i] * (X[i][:] @ W) ), K=128
template <int BN, bool AFP16>
__launch_bounds__(256, 4)
__global__ void k_gemm_mfma(const void* __restrict__ Xv, const _Float16* __restrict__ wsz,
                            const float* __restrict__ dinv, __half* __restrict__ out, int N) {
    constexpr int NT = BN / 16;
    constexpr int PAD = 8;
    __shared__ __align__(16) _Float16 smem[BN * 128];  // B frags; reused for epilogue

    const int tid = threadIdx.x;
    for (int i = tid; i < BN * 16; i += 256)
        *(uint4*)&smem[i << 3] = *(const uint4*)&wsz[i << 3];

    const int w = tid >> 6;
    const int lane = tid & 63;
    const int q = lane >> 4;
    const int m = lane & 15;
    const int row0 = blockIdx.x * 64;
    const int arow = row0 + w * 16 + m;
    const int arowc = arow < N ? arow : N - 1;

    float4v acc[NT];
#pragma unroll
    for (int nt = 0; nt < NT; ++nt) acc[nt] = (float4v){0.f, 0.f, 0.f, 0.f};

    __syncthreads();

#pragma unroll
    for (int kblk = 0; kblk < 4; ++kblk) {
        half8 af;
        if constexpr (AFP16) {
            const _Float16* A = (const _Float16*)Xv + (size_t)arowc * 128 + (q << 3);
            af = *(const half8*)(A + kblk * 32);
        } else {
            const float* A = (const float*)Xv + (size_t)arowc * 128 + (q << 3);
            float4 a0 = *(const float4*)(A + kblk * 32);
            float4 a1 = *(const float4*)(A + kblk * 32 + 4);
            af[0] = (_Float16)a0.x; af[1] = (_Float16)a0.y;
            af[2] = (_Float16)a0.z; af[3] = (_Float16)a0.w;
            af[4] = (_Float16)a1.x; af[5] = (_Float16)a1.y;
            af[6] = (_Float16)a1.z; af[7] = (_Float16)a1.w;
        }
#pragma unroll
        for (int nt = 0; nt < NT; ++nt) {
            half8 bf = *(const half8*)&smem[(((nt << 2) + kblk) << 9) + (lane << 3)];
            acc[nt] = __builtin_amdgcn_mfma_f32_16x16x32_f16(af, bf, acc[nt], 0, 0, 0);
        }
    }

    float s[4];
#pragma unroll
    for (int r = 0; r < 4; ++r) {
        int rr = row0 + w * 16 + q * 4 + r;
        s[r] = dinv[rr < N ? rr : N - 1];
    }
    __syncthreads();  // all B reads done before smem reuse
    _Float16* eb = smem;
#pragma unroll
    for (int nt = 0; nt < NT; ++nt)
#pragma unroll
        for (int r = 0; r < 4; ++r)
            eb[(w * 16 + q * 4 + r) * (BN + PAD) + nt * 16 + m] = (_Float16)(acc[nt][r] * s[r]);
    __syncthreads();
    constexpr int CPR = BN / 8;
    for (int i = tid; i < 64 * CPR; i += 256) {
        int row = i / CPR;
        int cf = (i % CPR) * 8;
        if (row0 + row < N)
            *(uint4*)&out[(size_t)(row0 + row) * BN + cf] = *(uint4*)&eb[row * (BN + PAD) + cf];
    }
}

// ---------------- d=128 aggregation, COLUMN-SPLIT x4 with XCD steering.
// Slice s (64 B = 32 fp16 cols) is processed only by blocks on XCD pair {2s,2s+1}
// (blockIdx%8 -> XCD). Per-XCD compulsory L2-miss footprint drops 256B -> 64B per row.
// Two nodes per wave; 4 lane-groups of 16 handle 4 edges; lane loads 1 uint (4B).
template <bool RELU>
__launch_bounds__(256)
__global__ void k_agg128(const __half* __restrict__ tp, const int* __restrict__ adj,
                         const int* __restrict__ startv, const int* __restrict__ deg,
                         const float* __restrict__ dinv, const float* __restrict__ bias,
                         _Float16* __restrict__ out, int N) {
    const int b = blockIdx.x;
    const int xcd = b & 7;
    const int sc = xcd >> 1;                       // column slice 0..3
    const int bis = ((b >> 3) << 1) | (xcd & 1);   // block-in-slice 0..12499
    const int n0 = (bis << 3) + ((threadIdx.x >> 6) << 1);
    const int lane = threadIdx.x & 63;
    if (n0 >= N) return;
    const bool has1 = (n0 + 1) < N;
    const int n1 = has1 ? n0 + 1 : n0;
    const int s0 = startv[n0], s1 = startv[n1];
    const int c0 = deg[n0];
    const int c1 = has1 ? deg[n1] : 0;
    const float one = 1.0f;
    const int g = lane >> 4;        // edge group 0..3
    const int sl = lane & 15;       // uint within 64B slice
    const unsigned* rowu = (const unsigned*)tp;    // row = 64 uints (256 B)
    const int co = sc * 16 + sl;                   // uint offset within row

    float a0[2] = {0.f, 0.f};
    float a1[2] = {0.f, 0.f};
    auto addrow = [&](float* acc, unsigned v) {
        fmix_lo(acc[0], v, one); fmix_hi(acc[1], v, one);
    };

    // self-loops
    {
        unsigned r0 = rowu[(size_t)n0 * 64 + co];
        unsigned r1 = rowu[(size_t)n1 * 64 + co];
        if (g == 0) { addrow(a0, r0); if (has1) addrow(a1, r1); }
    }

    // joint main loop: 8 gather instrs (32 cache lines) in flight per wave
    int e = 0;
    const int mc = min(c0, c1);
    for (; e + 16 <= mc; e += 16) {
        int j0[4], j1[4];
#pragma unroll
        for (int u = 0; u < 4; ++u) { j0[u] = adj[s0 + e + 4 * u + g]; j1[u] = adj[s1 + e + 4 * u + g]; }
        unsigned v0[4], v1[4];
#pragma unroll
        for (int u = 0; u < 4; ++u) { v0[u] = rowu[(size_t)j0[u] * 64 + co]; v1[u] = rowu[(size_t)j1[u] * 64 + co]; }
#pragma unroll
        for (int u = 0; u < 4; ++u) { addrow(a0, v0[u]); addrow(a1, v1[u]); }
    }

    auto finish = [&](float* acc, int s, int cnt, int eS) {
        int ee = eS;
        for (; ee + 16 <= cnt; ee += 16) {
            int j[4];
#pragma unroll
            for (int u = 0; u < 4; ++u) j[u] = adj[s + ee + 4 * u + g];
            unsigned v[4];
#pragma unroll
            for (int u = 0; u < 4; ++u) v[u] = rowu[(size_t)j[u] * 64 + co];
#pragma unroll
            for (int u = 0; u < 4; ++u) addrow(acc, v[u]);
        }
        if (ee + 8 <= cnt) {
            int j[2];
#pragma unroll
            for (int u = 0; u < 2; ++u) j[u] = adj[s + ee + 4 * u + g];
            unsigned v[2];
#pragma unroll
            for (int u = 0; u < 2; ++u) v[u] = rowu[(size_t)j[u] * 64 + co];
#pragma unroll
            for (int u = 0; u < 2; ++u) addrow(acc, v[u]);
            ee += 8;
        }
        if (ee + 4 <= cnt) {
            addrow(acc, rowu[(size_t)adj[s + ee + g] * 64 + co]);
            ee += 4;
        }
        if (ee + g < cnt)
            addrow(acc, rowu[(size_t)adj[s + ee + g] * 64 + co]);
    };
    finish(a0, s0, c0, e);
    if (has1) finish(a1, s1, c1, e);

#pragma unroll
    for (int i = 0; i < 2; ++i) {
        a0[i] += __shfl_xor(a0[i], 32);
        a0[i] += __shfl_xor(a0[i], 16);
        a1[i] += __shfl_xor(a1[i], 32);
        a1[i] += __shfl_xor(a1[i], 16);
    }
    if (g == 0) {
        const float bx = bias[sc * 32 + sl * 2];
        const float by = bias[sc * 32 + sl * 2 + 1];
        const float di0 = dinv[n0];
        float ox = di0 * a0[0] + bx, oy = di0 * a0[1] + by;
        if (RELU) { ox = fmaxf(ox, 0.f); oy = fmaxf(oy, 0.f); }
        __half2 ov = __floats2half2_rn(ox, oy);
        *(unsigned*)&out[(size_t)n0 * 128 + sc * 32 + sl * 2] = *(unsigned*)&ov;
        if (has1) {
            const float di1 = dinv[n1];
            ox = di1 * a1[0] + bx; oy = di1 * a1[1] + by;
            if (RELU) { ox = fmaxf(ox, 0.f); oy = fmaxf(oy, 0.f); }
            ov = __floats2half2_rn(ox, oy);
            *(unsigned*)&out[(size_t)n1 * 128 + sc * 32 + sl * 2] = *(unsigned*)&ov;
        }
    }
}

// ---------------- d=64 aggregation (fp32 out), COLUMN-SPLIT x2 with XCD steering.
// Slice s (64 B = 32 fp16 cols) on XCD quad {4s..4s+3}.
__launch_bounds__(256)
__global__ void k_agg64(const __half* __restrict__ tp, const int* __restrict__ adj,
                        const int* __restrict__ startv, const int* __restrict__ deg,
                        const float* __restrict__ dinv, const float* __restrict__ bias,
                        float* __restrict__ out, int N) {
    const int b = blockIdx.x;
    const int xcd = b & 7;
    const int sc = xcd >> 2;                       // column slice 0..1
    const int bis = ((b >> 3) << 2) | (xcd & 3);   // block-in-slice 0..12499
    const int n0 = (bis << 3) + ((threadIdx.x >> 6) << 1);
    const int lane = threadIdx.x & 63;
    if (n0 >= N) return;
    const bool has1 = (n0 + 1) < N;
    const int n1 = has1 ? n0 + 1 : n0;
    const int s0 = startv[n0], s1 = startv[n1];
    const int c0 = deg[n0];
    const int c1 = has1 ? deg[n1] : 0;
    const float one = 1.0f;
    const int g = lane >> 4;
    const int sl = lane & 15;
    const unsigned* rowu = (const unsigned*)tp;    // row = 32 uints (128 B)
    const int co = sc * 16 + sl;

    float a0[2] = {0.f, 0.f};
    float a1[2] = {0.f, 0.f};
    auto addrow = [&](float* acc, unsigned v) {
        fmix_lo(acc[0], v, one); fmix_hi(acc[1], v, one);
    };
    {
        unsigned r0 = rowu[(size_t)n0 * 32 + co];
        unsigned r1 = rowu[(size_t)n1 * 32 + co];
        if (g == 0) { addrow(a0, r0); if (has1) addrow(a1, r1); }
    }

    int e = 0;
    const int mc = min(c0, c1);
    for (; e + 16 <= mc; e += 16) {
        int j0[4], j1[4];
#pragma unroll
        for (int u = 0; u < 4; ++u) { j0[u] = adj[s0 + e + 4 * u + g]; j1[u] = adj[s1 + e + 4 * u + g]; }
        unsigned v0[4], v1[4];
#pragma unroll
        for (int u = 0; u < 4; ++u) { v0[u] = rowu[(size_t)j0[u] * 32 + co]; v1[u] = rowu[(size_t)j1[u] * 32 + co]; }
#pragma unroll
        for (int u = 0; u < 4; ++u) { addrow(a0, v0[u]); addrow(a1, v1[u]); }
    }

    auto finish = [&](float* acc, int s, int cnt, int eS) {
        int ee = eS;
        for (; ee + 16 <= cnt; ee += 16) {
            int j[4];
#pragma unroll
            for (int u = 0; u < 4; ++u) j[u] = adj[s + ee + 4 * u + g];
            unsigned v[4];
#pragma unroll
            for (int u = 0; u < 4; ++u) v[u] = rowu[(size_t)j[u] * 32 + co];
#pragma unroll
            for (int u = 0; u < 4; ++u) addrow(acc, v[u]);
        }
        if (ee + 8 <= cnt) {
            int j[2];
#pragma unroll
            for (int u = 0; u < 2; ++u) j[u] = adj[s + ee + 4 * u + g];
            unsigned v[2];
#pragma unroll
            for (int u = 0; u < 2; ++u) v[u] = rowu[(size_t)j[u] * 32 + co];
#pragma unroll
            for (int u = 0; u < 2; ++u) addrow(acc, v[u]);
            ee += 8;
        }
        if (ee + 4 <= cnt) {
            addrow(acc, rowu[(size_t)adj[s + ee + g] * 32 + co]);
            ee += 4;
        }
        if (ee + g < cnt)
            addrow(acc, rowu[(size_t)adj[s + ee + g] * 32 + co]);
    };
    finish(a0, s0, c0, e);
    if (has1) finish(a1, s1, c1, e);

#pragma unroll
    for (int i = 0; i < 2; ++i) {
        a0[i] += __shfl_xor(a0[i], 32);
        a0[i] += __shfl_xor(a0[i], 16);
        a1[i] += __shfl_xor(a1[i], 32);
        a1[i] += __shfl_xor(a1[i], 16);
    }
    if (g == 0) {
        const float bx = bias[sc * 32 + sl * 2];
        const float by = bias[sc * 32 + sl * 2 + 1];
        const float di0 = dinv[n0];
        float2 o;
        o.x = di0 * a0[0] + bx; o.y = di0 * a0[1] + by;
        *(float2*)&out[(size_t)n0 * 64 + sc * 32 + sl * 2] = o;
        if (has1) {
            const float di1 = dinv[n1];
            o.x = di1 * a1[0] + bx; o.y = di1 * a1[1] + by;
            *(float2*)&out[(size_t)n1 * 64 + sc * 32 + sl * 2] = o;
        }
    }
}

extern "C" void kernel_launch(void* const* d_in, const int* in_sizes, int n_in,
                              void* d_out, int out_size, void* d_ws, size_t ws_size,
                              hipStream_t stream) {
    const float* x  = (const float*)d_in[0];
    const int*   ei = (const int*)d_in[1];
    const float* W1 = (const float*)d_in[2];
    const float* b1 = (const float*)d_in[3];
    const float* W2 = (const float*)d_in[4];
    const float* b2 = (const float*)d_in[5];
    const float* W3 = (const float*)d_in[6];
    const float* b3 = (const float*)d_in[7];
    float* out = (float*)d_out;
    const int* src = ei;            // edge_index[0]
    const int* dst = ei + N_EDGES;  // edge_index[1]

    char* p = (char*)d_ws;
    __half* tp      = (__half*)p;    p += (size_t)N_NODES * 128 * 2;   // 25.6 MB
    _Float16* hbuf  = (_Float16*)p;  p += (size_t)N_NODES * 128 * 2;   // 25.6 MB
    int*   deg  = (int*)p;    p += (size_t)N_NODES * 4;
    float* dinv = (float*)p;  p += (size_t)N_NODES * 4;
    int*   stv  = (int*)p;    p += (size_t)N_NODES * 4;
    int*   bCur = (int*)p;    p += 1024;                               // bucket fill counts
    int*   adj  = (int*)p;    p += (size_t)NBUCKET * CAP * 4 + 16384;  // 7.0 MB bucketed
    _Float16* wz1 = (_Float16*)p; p += 16384 * 2;                      // 32 KB
    _Float16* wz2 = (_Float16*)p; p += 16384 * 2;                      // 32 KB
    _Float16* wz3 = (_Float16*)p; p += 8192 * 2;                       // 16 KB
    size_t need = (size_t)(p - (char*)d_ws);
    if (ws_size < need) return;  // visible failure rather than OOB

    int* ebuf = (int*)tp;  // 7.0 MB alias; tp not live until layer-1 GEMM

    hipMemsetAsync(bCur, 0, 1024, stream);
    k_part_wswz<<<276, 256, 0, stream>>>(src, dst, bCur, ebuf, N_EDGES,
                                         W1, W2, W3, wz1, wz2, wz3);
    k_bsort<<<NBUCKET, 256, 0, stream>>>(ebuf, bCur, adj, stv, deg, dinv, N_NODES);

    const int gb = (N_NODES + 63) / 64;
    const int ab128 = 12500 * 4;   // 4 column slices x 12500 blocks (8 nodes/block)
    const int ab64  = 12500 * 2;   // 2 column slices x 12500 blocks
    // layer 1: relu(agg(x@W1) + b1) -> fp16 hbuf
    k_gemm_mfma<128, false><<<gb, 256, 0, stream>>>(x, wz1, dinv, tp, N_NODES);
    k_agg128<true><<<ab128, 256, 0, stream>>>(tp, adj, stv, deg, dinv, b1, hbuf, N_NODES);
    // layer 2
    k_gemm_mfma<128, true><<<gb, 256, 0, stream>>>(hbuf, wz2, dinv, tp, N_NODES);
    k_agg128<true><<<ab128, 256, 0, stream>>>(tp, adj, stv, deg, dinv, b2, hbuf, N_NODES);
    // layer 3: agg(h@W3) + b3 (no relu) -> fp32 out
    k_gemm_mfma<64, true><<<gb, 256, 0, stream>>>(hbuf, wz3, dinv, tp, N_NODES);
    k_agg64<<<ab64, 256, 0, stream>>>(tp, adj, stv, deg, dinv, b3, out, N_NODES);
}